// Round 12
// baseline (793.616 us; speedup 1.0000x reference)
//
#include <hip/hip_runtime.h>
#include <hip/hip_bf16.h>

#define NB   64          // number of bins
#define NE   (NB + 1)    // number of edges
#define RC   32          // replica columns (one per bank)
#define ROWS (NB + 1)    // +1 trash row for invalid/masked-out elements

typedef float f32x4 __attribute__((ext_vector_type(4)));
typedef int   i32x4 __attribute__((ext_vector_type(4)));

// ---------------------------------------------------------------------------
// Branchless exact binning for affine (linspace) edges, verified bitwise per
// block. Guess is within 1 bin; one compare-adjust per direction. x == eN
// folds into the final min. Invalid -> row NB (trash).
// ---------------------------------------------------------------------------
#define BINV(x, mv, row)                                                     \
    {                                                                        \
        float t_ = ((x) - e0) * invstep;                                     \
        int g_ = (int)t_;                                                    \
        g_ = min(max(g_, 0), NB - 1);                                        \
        float gf_ = (float)g_;                                               \
        float lo_ = fmaf(gf_, step, e0);              /* == edges[g]   */    \
        float hi_ = fmaf(gf_ + 1.0f, step, e0);       /* == edges[g+1] */    \
        g_ += (hi_ <= (x)) ? 1 : 0;                                          \
        g_ -= (lo_ > (x)) ? 1 : 0;                                           \
        g_ = min(g_, NB - 1);                                                \
        bool valid_ = (mv) && ((x) >= e0) && ((x) <= eN);                    \
        (row) = valid_ ? g_ : NB;                                            \
    }

// Fallback: exact binning against arbitrary sorted edges (LDS pairs, loops).
__device__ __forceinline__ int bin_lds(float x, const float2* __restrict__ ep,
                                       float e0, float eN, float invstep) {
    if (!(x >= e0) || !(x <= eN)) return -1;
    if (x == eN) return NB - 1;
    int g = (int)((x - e0) * invstep);
    g = min(max(g, 0), NB - 1);
    float2 p = ep[g];
    while (p.x > x) { --g; p = ep[g]; }
    while (p.y <= x) { ++g; p = ep[g]; }
    return g;
}

__device__ __forceinline__ float wave_sum64(float v) {
    for (int o = 32; o > 0; o >>= 1) v += __shfl_xor(v, o, 64);
    return v;
}
__device__ __forceinline__ float wave_incl_scan64(float v, int lane) {
    for (int d = 1; d < 64; d <<= 1) {
        float u = __shfl_up(v, d, 64);
        if (lane >= d) v += u;
    }
    return v;
}

// ---------------------------------------------------------------------------
// Streaming phase: non-temporal loads (bypass L1 allocation -- R10: lifts the
// ~3.1 TB/s L1 miss-concurrency ceiling). 2x unroll (R10-best).
// LDS hist layout [2][65][32]: bank = lane&31 always -> conflict-free.
// ---------------------------------------------------------------------------
template <bool AFFINE>
__device__ __forceinline__ void
stream_hist(const f32x4* __restrict__ o4, const f32x4* __restrict__ p4,
            const i32x4* __restrict__ m4, int startV, int endV, int tid,
            unsigned int* __restrict__ hobs, unsigned int* __restrict__ hpred,
            const float2* __restrict__ s_epair,
            float e0, float eN, float step, float invstep)
{
#define PROC(o, q, m)                                                        \
    do {                                                                     \
        int r0, r1, r2, r3, r4, r5, r6, r7;                                  \
        if (AFFINE) {                                                        \
            BINV((o)[0], (m)[0], r0); BINV((q)[0], (m)[0], r1);              \
            BINV((o)[1], (m)[1], r2); BINV((q)[1], (m)[1], r3);              \
            BINV((o)[2], (m)[2], r4); BINV((q)[2], (m)[2], r5);              \
            BINV((o)[3], (m)[3], r6); BINV((q)[3], (m)[3], r7);              \
        } else {                                                             \
            int t;                                                           \
            t = bin_lds((o)[0], s_epair, e0, eN, invstep);                   \
            r0 = ((m)[0] && t >= 0) ? t : NB;                                \
            t = bin_lds((q)[0], s_epair, e0, eN, invstep);                   \
            r1 = ((m)[0] && t >= 0) ? t : NB;                                \
            t = bin_lds((o)[1], s_epair, e0, eN, invstep);                   \
            r2 = ((m)[1] && t >= 0) ? t : NB;                                \
            t = bin_lds((q)[1], s_epair, e0, eN, invstep);                   \
            r3 = ((m)[1] && t >= 0) ? t : NB;                                \
            t = bin_lds((o)[2], s_epair, e0, eN, invstep);                   \
            r4 = ((m)[2] && t >= 0) ? t : NB;                                \
            t = bin_lds((q)[2], s_epair, e0, eN, invstep);                   \
            r5 = ((m)[2] && t >= 0) ? t : NB;                                \
            t = bin_lds((o)[3], s_epair, e0, eN, invstep);                   \
            r6 = ((m)[3] && t >= 0) ? t : NB;                                \
            t = bin_lds((q)[3], s_epair, e0, eN, invstep);                   \
            r7 = ((m)[3] && t >= 0) ? t : NB;                                \
        }                                                                    \
        atomicAdd(hobs  + (r0 << 5), 1u);                                    \
        atomicAdd(hpred + (r1 << 5), 1u);                                    \
        atomicAdd(hobs  + (r2 << 5), 1u);                                    \
        atomicAdd(hpred + (r3 << 5), 1u);                                    \
        atomicAdd(hobs  + (r4 << 5), 1u);                                    \
        atomicAdd(hpred + (r5 << 5), 1u);                                    \
        atomicAdd(hobs  + (r6 << 5), 1u);                                    \
        atomicAdd(hpred + (r7 << 5), 1u);                                    \
    } while (0)

    int i = startV + tid;
    for (; i + 256 < endV; i += 512) {
        f32x4 o0 = __builtin_nontemporal_load(o4 + i);
        f32x4 q0 = __builtin_nontemporal_load(p4 + i);
        i32x4 m0 = __builtin_nontemporal_load(m4 + i);
        f32x4 o1 = __builtin_nontemporal_load(o4 + i + 256);
        f32x4 q1 = __builtin_nontemporal_load(p4 + i + 256);
        i32x4 m1 = __builtin_nontemporal_load(m4 + i + 256);
        PROC(o0, q0, m0);
        PROC(o1, q1, m1);
    }
    for (; i < endV; i += 256) {
        f32x4 o = __builtin_nontemporal_load(o4 + i);
        f32x4 q = __builtin_nontemporal_load(p4 + i);
        i32x4 m = __builtin_nontemporal_load(m4 + i);
        PROC(o, q, m);
    }
#undef PROC
}

// ---------------------------------------------------------------------------
// Fused kernel: histogram stream + (last block) finalize.
// ws layout: counts[2][B][NB] (uint32), then done-counter (uint32).
// out[0] = w2_loss, out[1 .. 1+B*NB) = p_obs, out[1+B*NB ..) = p_pred
// ---------------------------------------------------------------------------
__global__ void __launch_bounds__(256, 8)
hist_kernel(const float* __restrict__ obs,
            const float* __restrict__ pred,
            const int*   __restrict__ mask,
            const float* __restrict__ edges,
            const float* __restrict__ bweights,
            unsigned int* __restrict__ counts,
            unsigned int* __restrict__ done,
            float* __restrict__ out,
            int elemsPerBatch, int blocksPerBatch, int B)
{
    __shared__ unsigned int s_hist[2][ROWS][RC];
    __shared__ float2       s_epair[NB];
    __shared__ int          s_affine;
    __shared__ int          s_last;
    __shared__ float        s_loss[4];

    const int tid = threadIdx.x;
    for (int i = tid; i < 2 * ROWS * RC; i += 256)
        (&s_hist[0][0][0])[i] = 0u;
    if (tid < NB) s_epair[tid] = make_float2(edges[tid], edges[tid + 1]);
    if (tid == 0) s_affine = 1;
    __syncthreads();

    const float e0 = edges[0];
    const float eN = edges[NB];
    const float step    = (eN - e0) / (float)NB;
    const float invstep = 1.0f / step;

    // verify register-reconstruction is bitwise-faithful to the edge array
    if (tid < NE) {
        float recon = fmaf((float)tid, step, e0);
        if (!(recon == edges[tid]) || !(step > 0.0f)) atomicAnd(&s_affine, 0);
    }
    __syncthreads();
    const bool affine = (s_affine != 0);

    const int b     = blockIdx.x / blocksPerBatch;
    const int chunk = blockIdx.x % blocksPerBatch;
    const int perBlock = elemsPerBatch / blocksPerBatch;
    const size_t base  = (size_t)b * (size_t)elemsPerBatch;

    const f32x4* o4 = reinterpret_cast<const f32x4*>(obs  + base);
    const f32x4* p4 = reinterpret_cast<const f32x4*>(pred + base);
    const i32x4* m4 = reinterpret_cast<const i32x4*>(mask + base);

    const int startV = (chunk * perBlock) >> 2;
    const int endV   = startV + (perBlock >> 2);

    const int c = tid & (RC - 1);
    unsigned int* hobs  = &s_hist[0][0][0] + c;
    unsigned int* hpred = &s_hist[1][0][0] + c;

    if (affine)
        stream_hist<true >(o4, p4, m4, startV, endV, tid, hobs, hpred,
                           s_epair, e0, eN, step, invstep);
    else
        stream_hist<false>(o4, p4, m4, startV, endV, tid, hobs, hpred,
                           s_epair, e0, eN, step, invstep);

    __syncthreads();

    if (tid < NB) {
        unsigned int so = 0u, sp = 0u;
        #pragma unroll
        for (int r = 0; r < RC; ++r) {
            int col = (tid + r) & (RC - 1);      // rotated -> conflict-free
            so += s_hist[0][tid][col];
            sp += s_hist[1][tid][col];
        }
        if (so) atomicAdd(&counts[(size_t)b * NB + tid], so);
        if (sp) atomicAdd(&counts[(size_t)B * NB + (size_t)b * NB + tid], sp);
    }

    // ---- last-block-finalize handshake ----
    __threadfence();                      // make count atomics globally visible
    if (tid == 0) {
        unsigned int old = atomicAdd(done, 1u);
        s_last = (old == gridDim.x - 1u) ? 1 : 0;
    }
    __syncthreads();
    if (!s_last) return;

    // ---- finalize (one block, 4 waves; wave w -> batches w, w+4, ...) ----
    const int w    = tid >> 6;
    const int lane = tid & 63;

    float midA = 0.5f * (edges[lane] + edges[lane + 1]);
    float width;
    if (lane < NB - 1) {
        float midB = 0.5f * (edges[lane + 1] + edges[lane + 2]);
        width = midB - midA;
    } else {
        float midPrev = 0.5f * (edges[NB - 2] + edges[NB - 1]);
        width = midA - midPrev;
    }
    const float bw = bweights[lane];

    float loss_acc = 0.0f;
    for (int bb = w; bb < B; bb += 4) {
        // agent-scope loads: dodge stale per-XCD L2 lines for counts
        unsigned int co_u = __hip_atomic_load(
            &counts[(size_t)bb * NB + lane],
            __ATOMIC_RELAXED, __HIP_MEMORY_SCOPE_AGENT);
        unsigned int cp_u = __hip_atomic_load(
            &counts[(size_t)B * NB + (size_t)bb * NB + lane],
            __ATOMIC_RELAXED, __HIP_MEMORY_SCOPE_AGENT);
        float co = (float)co_u;
        float cp = (float)cp_u;

        float to = wave_sum64(co);
        if (to == 0.0f) { co = 1.0f; to = 64.0f; }
        float tp = wave_sum64(cp);
        if (tp == 0.0f) { cp = 1.0f; tp = 64.0f; }

        float po = co / to;
        float pp = cp / tp;
        out[1 + (size_t)bb * NB + lane]                  = po;
        out[1 + (size_t)B * NB + (size_t)bb * NB + lane] = pp;

        float cdfo = wave_incl_scan64(po, lane);
        float cdfp = wave_incl_scan64(pp, lane);
        float d = cdfo - cdfp;
        float wd = d * d * width * bw;
        float s = wave_sum64(wd);
        if (lane == 0) loss_acc += s;
    }
    if (lane == 0) s_loss[w] = loss_acc;
    __syncthreads();
    if (tid == 0)
        out[0] = (s_loss[0] + s_loss[1] + s_loss[2] + s_loss[3]) / (float)B;
}

// ---------------------------------------------------------------------------
extern "C" void kernel_launch(void* const* d_in, const int* in_sizes, int n_in,
                              void* d_out, int out_size, void* d_ws, size_t ws_size,
                              hipStream_t stream) {
    const float* obs      = (const float*)d_in[0];
    const float* pred     = (const float*)d_in[1];
    const int*   mask     = (const int*)d_in[2];
    const float* edges    = (const float*)d_in[3];
    const float* bweights = (const float*)d_in[4];
    float* out = (float*)d_out;

    const int nb = in_sizes[3] - 1;                 // 64
    const int B  = (out_size - 1) / (2 * nb);       // 32
    const int elemsPerBatch = in_sizes[0] / B;      // 1048576

    unsigned int* counts = (unsigned int*)d_ws;     // [2][B][nb] uint32
    unsigned int* done   = counts + (size_t)2 * B * nb;
    const size_t zeroBytes = ((size_t)2 * B * nb + 1) * sizeof(unsigned int);

    hipMemsetAsync(d_ws, 0, zeroBytes, stream);

    const int blocksPerBatch = 128;                 // 8192 elems / block
    dim3 grid(B * blocksPerBatch), block(256);
    hist_kernel<<<grid, block, 0, stream>>>(obs, pred, mask, edges, bweights,
                                            counts, done, out,
                                            elemsPerBatch, blocksPerBatch, B);
}

// Round 13
// 79.458 us; speedup vs baseline: 9.9878x; 9.9878x over previous
//
#include <hip/hip_runtime.h>
#include <hip/hip_bf16.h>

#define NB   64          // number of bins
#define NE   (NB + 1)    // number of edges
#define RC   32          // replica columns (one per bank)
#define ROWS (NB + 1)    // +1 trash row for invalid/masked-out elements

typedef float f32x4 __attribute__((ext_vector_type(4)));
typedef int   i32x4 __attribute__((ext_vector_type(4)));

// ---------------------------------------------------------------------------
// Branchless exact binning for affine (linspace) edges, verified bitwise per
// block. Guess is within 1 bin; one compare-adjust per direction. x == eN
// folds into the final min. Invalid -> row NB (trash).
// ---------------------------------------------------------------------------
#define BINV(x, mv, row)                                                     \
    {                                                                        \
        float t_ = ((x) - e0) * invstep;                                     \
        int g_ = (int)t_;                                                    \
        g_ = min(max(g_, 0), NB - 1);                                        \
        float gf_ = (float)g_;                                               \
        float lo_ = fmaf(gf_, step, e0);              /* == edges[g]   */    \
        float hi_ = fmaf(gf_ + 1.0f, step, e0);       /* == edges[g+1] */    \
        g_ += (hi_ <= (x)) ? 1 : 0;                                          \
        g_ -= (lo_ > (x)) ? 1 : 0;                                           \
        g_ = min(g_, NB - 1);                                                \
        bool valid_ = (mv) && ((x) >= e0) && ((x) <= eN);                    \
        (row) = valid_ ? g_ : NB;                                            \
    }

// Fallback: exact binning against arbitrary sorted edges (LDS pairs, loops).
__device__ __forceinline__ int bin_lds(float x, const float2* __restrict__ ep,
                                       float e0, float eN, float invstep) {
    if (!(x >= e0) || !(x <= eN)) return -1;
    if (x == eN) return NB - 1;
    int g = (int)((x - e0) * invstep);
    g = min(max(g, 0), NB - 1);
    float2 p = ep[g];
    while (p.x > x) { --g; p = ep[g]; }
    while (p.y <= x) { ++g; p = ep[g]; }
    return g;
}

__device__ __forceinline__ float wave_sum64(float v) {
    for (int o = 32; o > 0; o >>= 1) v += __shfl_xor(v, o, 64);
    return v;
}
__device__ __forceinline__ float wave_incl_scan64(float v, int lane) {
    for (int d = 1; d < 64; d <<= 1) {
        float u = __shfl_up(v, d, 64);
        if (lane >= d) v += u;
    }
    return v;
}

// ---------------------------------------------------------------------------
// Kernel 1: fused dual masked histogram. Non-temporal streaming loads
// (bypass L1 allocation -- R10: lifts the ~3.1 TB/s L1 miss-concurrency
// ceiling). 2x unroll (R10-best). LDS hist layout [2][65][32]: bank =
// lane&31 always -> data-independent, conflict-free.
// ---------------------------------------------------------------------------
template <bool AFFINE>
__device__ __forceinline__ void
stream_hist(const f32x4* __restrict__ o4, const f32x4* __restrict__ p4,
            const i32x4* __restrict__ m4, int startV, int endV, int tid,
            unsigned int* __restrict__ hobs, unsigned int* __restrict__ hpred,
            const float2* __restrict__ s_epair,
            float e0, float eN, float step, float invstep)
{
#define PROC(o, q, m)                                                        \
    do {                                                                     \
        int r0, r1, r2, r3, r4, r5, r6, r7;                                  \
        if (AFFINE) {                                                        \
            BINV((o)[0], (m)[0], r0); BINV((q)[0], (m)[0], r1);              \
            BINV((o)[1], (m)[1], r2); BINV((q)[1], (m)[1], r3);              \
            BINV((o)[2], (m)[2], r4); BINV((q)[2], (m)[2], r5);              \
            BINV((o)[3], (m)[3], r6); BINV((q)[3], (m)[3], r7);              \
        } else {                                                             \
            int t;                                                           \
            t = bin_lds((o)[0], s_epair, e0, eN, invstep);                   \
            r0 = ((m)[0] && t >= 0) ? t : NB;                                \
            t = bin_lds((q)[0], s_epair, e0, eN, invstep);                   \
            r1 = ((m)[0] && t >= 0) ? t : NB;                                \
            t = bin_lds((o)[1], s_epair, e0, eN, invstep);                   \
            r2 = ((m)[1] && t >= 0) ? t : NB;                                \
            t = bin_lds((q)[1], s_epair, e0, eN, invstep);                   \
            r3 = ((m)[1] && t >= 0) ? t : NB;                                \
            t = bin_lds((o)[2], s_epair, e0, eN, invstep);                   \
            r4 = ((m)[2] && t >= 0) ? t : NB;                                \
            t = bin_lds((q)[2], s_epair, e0, eN, invstep);                   \
            r5 = ((m)[2] && t >= 0) ? t : NB;                                \
            t = bin_lds((o)[3], s_epair, e0, eN, invstep);                   \
            r6 = ((m)[3] && t >= 0) ? t : NB;                                \
            t = bin_lds((q)[3], s_epair, e0, eN, invstep);                   \
            r7 = ((m)[3] && t >= 0) ? t : NB;                                \
        }                                                                    \
        atomicAdd(hobs  + (r0 << 5), 1u);                                    \
        atomicAdd(hpred + (r1 << 5), 1u);                                    \
        atomicAdd(hobs  + (r2 << 5), 1u);                                    \
        atomicAdd(hpred + (r3 << 5), 1u);                                    \
        atomicAdd(hobs  + (r4 << 5), 1u);                                    \
        atomicAdd(hpred + (r5 << 5), 1u);                                    \
        atomicAdd(hobs  + (r6 << 5), 1u);                                    \
        atomicAdd(hpred + (r7 << 5), 1u);                                    \
    } while (0)

    int i = startV + tid;
    for (; i + 256 < endV; i += 512) {
        f32x4 o0 = __builtin_nontemporal_load(o4 + i);
        f32x4 q0 = __builtin_nontemporal_load(p4 + i);
        i32x4 m0 = __builtin_nontemporal_load(m4 + i);
        f32x4 o1 = __builtin_nontemporal_load(o4 + i + 256);
        f32x4 q1 = __builtin_nontemporal_load(p4 + i + 256);
        i32x4 m1 = __builtin_nontemporal_load(m4 + i + 256);
        PROC(o0, q0, m0);
        PROC(o1, q1, m1);
    }
    for (; i < endV; i += 256) {
        f32x4 o = __builtin_nontemporal_load(o4 + i);
        f32x4 q = __builtin_nontemporal_load(p4 + i);
        i32x4 m = __builtin_nontemporal_load(m4 + i);
        PROC(o, q, m);
    }
#undef PROC
}

__global__ void __launch_bounds__(256, 8)
hist_kernel(const float* __restrict__ obs,
            const float* __restrict__ pred,
            const int*   __restrict__ mask,
            const float* __restrict__ edges,
            unsigned int* __restrict__ counts,   // [2][B][NB]
            int elemsPerBatch, int blocksPerBatch, int B)
{
    __shared__ unsigned int s_hist[2][ROWS][RC];
    __shared__ float2       s_epair[NB];
    __shared__ int          s_affine;

    const int tid = threadIdx.x;
    for (int i = tid; i < 2 * ROWS * RC; i += 256)
        (&s_hist[0][0][0])[i] = 0u;
    if (tid < NB) s_epair[tid] = make_float2(edges[tid], edges[tid + 1]);
    if (tid == 0) s_affine = 1;
    __syncthreads();

    const float e0 = edges[0];
    const float eN = edges[NB];
    const float step    = (eN - e0) / (float)NB;
    const float invstep = 1.0f / step;

    // verify register-reconstruction is bitwise-faithful to the edge array
    if (tid < NE) {
        float recon = fmaf((float)tid, step, e0);
        if (!(recon == edges[tid]) || !(step > 0.0f)) atomicAnd(&s_affine, 0);
    }
    __syncthreads();
    const bool affine = (s_affine != 0);

    const int b     = blockIdx.x / blocksPerBatch;
    const int chunk = blockIdx.x % blocksPerBatch;
    const int perBlock = elemsPerBatch / blocksPerBatch;
    const size_t base  = (size_t)b * (size_t)elemsPerBatch;

    const f32x4* o4 = reinterpret_cast<const f32x4*>(obs  + base);
    const f32x4* p4 = reinterpret_cast<const f32x4*>(pred + base);
    const i32x4* m4 = reinterpret_cast<const i32x4*>(mask + base);

    const int startV = (chunk * perBlock) >> 2;
    const int endV   = startV + (perBlock >> 2);

    const int c = tid & (RC - 1);
    unsigned int* hobs  = &s_hist[0][0][0] + c;
    unsigned int* hpred = &s_hist[1][0][0] + c;

    if (affine)
        stream_hist<true >(o4, p4, m4, startV, endV, tid, hobs, hpred,
                           s_epair, e0, eN, step, invstep);
    else
        stream_hist<false>(o4, p4, m4, startV, endV, tid, hobs, hpred,
                           s_epair, e0, eN, step, invstep);

    __syncthreads();

    if (tid < NB) {
        unsigned int so = 0u, sp = 0u;
        #pragma unroll
        for (int r = 0; r < RC; ++r) {
            int col = (tid + r) & (RC - 1);      // rotated -> conflict-free
            so += s_hist[0][tid][col];
            sp += s_hist[1][tid][col];
        }
        if (so) atomicAdd(&counts[(size_t)b * NB + tid], so);
        if (sp) atomicAdd(&counts[(size_t)B * NB + (size_t)b * NB + tid], sp);
    }
}

// ---------------------------------------------------------------------------
// Kernel 2: finalize, 4 waves in parallel (wave w -> batches w, w+4, ...).
// Deterministic: loss partials combined in fixed order by thread 0.
// out[0] = w2_loss, out[1 .. 1+B*NB) = p_obs, out[1+B*NB ..) = p_pred
// ---------------------------------------------------------------------------
__global__ void __launch_bounds__(256)
finalize_kernel(const unsigned int* __restrict__ counts,
                const float* __restrict__ edges,
                const float* __restrict__ bweights,
                float* __restrict__ out, int B)
{
    __shared__ float s_loss[4];
    const int tid  = threadIdx.x;
    const int w    = tid >> 6;
    const int lane = tid & 63;    // == bin index

    float midA = 0.5f * (edges[lane] + edges[lane + 1]);
    float width;
    if (lane < NB - 1) {
        float midB = 0.5f * (edges[lane + 1] + edges[lane + 2]);
        width = midB - midA;
    } else {
        float midPrev = 0.5f * (edges[NB - 2] + edges[NB - 1]);
        width = midA - midPrev;
    }
    const float bw = bweights[lane];

    float loss_acc = 0.0f;
    for (int b = w; b < B; b += 4) {
        float co = (float)counts[(size_t)b * NB + lane];
        float cp = (float)counts[(size_t)B * NB + (size_t)b * NB + lane];

        float to = wave_sum64(co);
        if (to == 0.0f) { co = 1.0f; to = 64.0f; }
        float tp = wave_sum64(cp);
        if (tp == 0.0f) { cp = 1.0f; tp = 64.0f; }

        float po = co / to;
        float pp = cp / tp;
        out[1 + (size_t)b * NB + lane]                  = po;
        out[1 + (size_t)B * NB + (size_t)b * NB + lane] = pp;

        float cdfo = wave_incl_scan64(po, lane);
        float cdfp = wave_incl_scan64(pp, lane);
        float d = cdfo - cdfp;
        float wd = d * d * width * bw;
        float s = wave_sum64(wd);
        if (lane == 0) loss_acc += s;
    }
    if (lane == 0) s_loss[w] = loss_acc;
    __syncthreads();
    if (tid == 0)
        out[0] = (s_loss[0] + s_loss[1] + s_loss[2] + s_loss[3]) / (float)B;
}

// ---------------------------------------------------------------------------
extern "C" void kernel_launch(void* const* d_in, const int* in_sizes, int n_in,
                              void* d_out, int out_size, void* d_ws, size_t ws_size,
                              hipStream_t stream) {
    const float* obs      = (const float*)d_in[0];
    const float* pred     = (const float*)d_in[1];
    const int*   mask     = (const int*)d_in[2];
    const float* edges    = (const float*)d_in[3];
    const float* bweights = (const float*)d_in[4];
    float* out = (float*)d_out;

    const int nb = in_sizes[3] - 1;                 // 64
    const int B  = (out_size - 1) / (2 * nb);       // 32
    const int elemsPerBatch = in_sizes[0] / B;      // 1048576

    unsigned int* counts = (unsigned int*)d_ws;     // [2][B][nb] uint32
    const size_t countsBytes = (size_t)2 * B * nb * sizeof(unsigned int);

    hipMemsetAsync(d_ws, 0, countsBytes, stream);

    const int blocksPerBatch = 128;                 // 8192 elems / block
    dim3 grid(B * blocksPerBatch), block(256);
    hist_kernel<<<grid, block, 0, stream>>>(obs, pred, mask, edges, counts,
                                            elemsPerBatch, blocksPerBatch, B);

    finalize_kernel<<<1, 256, 0, stream>>>(counts, edges, bweights, out, B);
}